// Round 2
// baseline (243.196 us; speedup 1.0000x reference)
//
#include <hip/hip_runtime.h>

// RINN controller: B=131072, n_k=64, n_w=128, n_y=16, n_u=16, N_PLANT=16
// xi layout per row: [ y (16) | x_k (64) ]  (80 floats)
//
// Strategy R1: fp32 VALU, one thread per batch element.
//   base[i] = sum_k xi[k] * E[k][i]      (E = transposed [Dvy | Cv], 80x128)
//   u[r]   += sum_k xi[k] * F[k][r]      (F = transposed [Duy | Cu], 80x16)
//   solve (scatter form, j = 127..0):
//     w_j = relu(base[j]); u[r] += DuwT[j][r]*w_j; base[i<j] += DvwT[j][i]*w_j
// Matrices are transposed into d_ws by a small prep kernel so every unrolled
// row access is a contiguous, wave-uniform s_load.

#define NW 128
#define NK 64
#define NY 16
#define NU 16
#define NXI 80

// ws layout in floats
#define E_OFF    0        // [80][128] = 10240
#define F_OFF    10240    // [80][16]  = 1280
#define DVWT_OFF 11520    // [128][128]= 16384
#define DUWT_OFF 27904    // [128][16] = 2048
#define WS_FLOATS 29952

__global__ void prep_kernel(const float* __restrict__ Cv,
                            const float* __restrict__ Dvw,
                            const float* __restrict__ Dvy,
                            const float* __restrict__ Cu,
                            const float* __restrict__ Duw,
                            const float* __restrict__ Duy,
                            float* __restrict__ ws) {
    int idx = blockIdx.x * blockDim.x + threadIdx.x;
    if (idx >= WS_FLOATS) return;
    float v;
    if (idx < F_OFF) {                       // E[k][i], k=0..79, i=0..127
        int k = idx >> 7, i = idx & 127;
        v = (k < NY) ? Dvy[i * NY + k] : Cv[i * NK + (k - NY)];
    } else if (idx < DVWT_OFF) {             // F[k][r]
        int t = idx - F_OFF;
        int k = t >> 4, r = t & 15;
        v = (k < NY) ? Duy[r * NY + k] : Cu[r * NK + (k - NY)];
    } else if (idx < DUWT_OFF) {             // DvwT[j][i] = Dvw[i][j]
        int t = idx - DVWT_OFF;
        int j = t >> 7, i = t & 127;
        v = Dvw[i * NW + j];
    } else {                                 // DuwT[j][r] = Duw[r][j]
        int t = idx - DUWT_OFF;
        int j = t >> 4, r = t & 15;
        v = Duw[r * NW + j];
    }
    ws[idx] = v;
}

__global__ __launch_bounds__(256) void rinn_main(const float* __restrict__ xi,
                                                 const float* __restrict__ ws,
                                                 float* __restrict__ out) {
    const int b = blockIdx.x * 256 + threadIdx.x;

    const float* __restrict__ E    = ws + E_OFF;
    const float* __restrict__ F    = ws + F_OFF;
    const float* __restrict__ DvwT = ws + DVWT_OFF;
    const float* __restrict__ DuwT = ws + DUWT_OFF;

    float base[NW];
    float u[NU];
#pragma unroll
    for (int i = 0; i < NW; ++i) base[i] = 0.f;
#pragma unroll
    for (int r = 0; r < NU; ++r) u[r] = 0.f;

    const float4* __restrict__ xi4 =
        reinterpret_cast<const float4*>(xi + (size_t)b * NXI);

    // Dense input part: base += E^T-gathered, u += F part.
    for (int kk = 0; kk < NXI / 4; ++kk) {
        float4 xv = xi4[kk];
        float xs[4] = {xv.x, xv.y, xv.z, xv.w};
#pragma unroll
        for (int c = 0; c < 4; ++c) {
            const float x = xs[c];
            const float* __restrict__ Ek = E + (kk * 4 + c) * NW;
            const float* __restrict__ Fk = F + (kk * 4 + c) * NU;
#pragma unroll
            for (int i = 0; i < NW; ++i) base[i] = fmaf(x, Ek[i], base[i]);
#pragma unroll
            for (int r = 0; r < NU; ++r) u[r] = fmaf(x, Fk[r], u[r]);
        }
    }

    // Triangular solve (scatter form), fully unrolled, static indices only.
#pragma unroll
    for (int j = NW - 1; j >= 0; --j) {
        const float wj = fmaxf(base[j], 0.f);
        const float* __restrict__ Dj = DuwT + j * NU;
#pragma unroll
        for (int r = 0; r < NU; ++r) u[r] = fmaf(wj, Dj[r], u[r]);
        const float* __restrict__ Vj = DvwT + j * NW;
#pragma unroll
        for (int i = 0; i < j; ++i) base[i] = fmaf(wj, Vj[i], base[i]);
    }

    float4* __restrict__ out4 = reinterpret_cast<float4*>(out + (size_t)b * NU);
#pragma unroll
    for (int q = 0; q < 4; ++q)
        out4[q] = make_float4(u[q * 4 + 0], u[q * 4 + 1], u[q * 4 + 2], u[q * 4 + 3]);
}

extern "C" void kernel_launch(void* const* d_in, const int* in_sizes, int n_in,
                              void* d_out, int out_size, void* d_ws, size_t ws_size,
                              hipStream_t stream) {
    const float* xi  = (const float*)d_in[0];
    const float* Cv  = (const float*)d_in[1];
    const float* Dvw = (const float*)d_in[2];
    const float* Dvy = (const float*)d_in[3];
    const float* Cu  = (const float*)d_in[4];
    const float* Duw = (const float*)d_in[5];
    const float* Duy = (const float*)d_in[6];
    float* out = (float*)d_out;
    float* ws  = (float*)d_ws;

    const int B = in_sizes[0] / NXI;  // 131072

    prep_kernel<<<(WS_FLOATS + 255) / 256, 256, 0, stream>>>(Cv, Dvw, Dvy, Cu, Duw, Duy, ws);
    rinn_main<<<B / 256, 256, 0, stream>>>(xi, ws, out);
}